// Round 2
// baseline (186.624 us; speedup 1.0000x reference)
//
#include <hip/hip_runtime.h>

// ---------------- problem constants ----------------
#define HH 16
#define DD 64
#define SQ 1024          // queries
#define LW 8192          // attention window (keys)
#define OLDK 7168        // old (already-RoPE'd) keys in window
#define CACHE_BASE 2560  // cache row index of window position 0
#define SFRAME 9728      // START_FRAME
#define KSPLIT 8
#define KPER (LW / KSPLIT)   // 1024 keys per split
#define NSTEP (KPER / 64)    // 16 K-steps of 64 keys

// ws layout (bytes)
#define KB_OFF 0u                    // bf16 Kb[h][8192][64]   = 16 MiB
#define VT_OFF 16777216u             // bf16 Vt[h][64][8192]   = 16 MiB
#define QB_OFF 33554432u             // bf16 Qb[h][1024][64]   =  2 MiB
#define OP_OFF 35651584u             // f32 Op[ks][h][1024][64]= 32 MiB
#define LP_OFF 69206016u             // f32 Lp[ks][h][1024]    = 512 KiB
// total ~66.5 MiB of ws

typedef __bf16 bf16x8 __attribute__((ext_vector_type(8)));
typedef float floatx16 __attribute__((ext_vector_type(16)));
typedef unsigned uintx2 __attribute__((ext_vector_type(2)));
typedef unsigned uintx4 __attribute__((ext_vector_type(4)));

__device__ __forceinline__ unsigned short f2bf(float f) {
  unsigned u = __builtin_bit_cast(unsigned, f);
  u += 0x7fffu + ((u >> 16) & 1u);           // RNE
  return (unsigned short)(u >> 16);
}

__device__ __forceinline__ float fast_exp2(float x) {
#if __has_builtin(__builtin_amdgcn_exp2f)
  return __builtin_amdgcn_exp2f(x);
#else
  return __builtin_exp2f(x);
#endif
}

// pack two f32 -> bf16x2 (as uint). element0 = a (low 16), element1 = b.
__device__ __forceinline__ unsigned pack_bf2(float a, float b) {
#if __has_builtin(__builtin_amdgcn_cvt_pk_bf16_f32)
  typedef __bf16 bf16x2_t __attribute__((ext_vector_type(2)));
  bf16x2_t r = __builtin_amdgcn_cvt_pk_bf16_f32(a, b);
  return __builtin_bit_cast(unsigned, r);
#else
  unsigned ua = __builtin_bit_cast(unsigned, a) + 0x8000u;  // round-half-up
  unsigned ub = __builtin_bit_cast(unsigned, b) + 0x8000u;
  return __builtin_amdgcn_perm(ub, ua, 0x07060302);         // [ua.hi16 | ub.hi16]
#endif
}

__device__ __forceinline__ void async16(void* lds, const void* g) {
  __builtin_amdgcn_global_load_lds((__attribute__((address_space(1))) void*)(g),
                                   (__attribute__((address_space(3))) void*)(lds),
                                   16, 0, 0);
}

// ---------------- prepass: build bf16 Kb / Vt(transposed) / Qb(rope*scale) ----
__global__ __launch_bounds__(256) void prepass(
    const float* __restrict__ qin, const float* __restrict__ kin,
    const float* __restrict__ vin, const float* __restrict__ ck,
    const float* __restrict__ cv, const float* __restrict__ fc,
    const float* __restrict__ fs, unsigned short* __restrict__ Kb,
    unsigned short* __restrict__ Vt, unsigned short* __restrict__ Qb) {
  int b = blockIdx.x, t = threadIdx.x;
  if (b < 2048) {
    // V transpose: 64kk x 64d tile -> Vt[h][d][kk]
    __shared__ float tl[64 * 65];
    int h = b >> 7, kk0 = (b & 127) * 64;
    int col = t & 63, rb = t >> 6;
#pragma unroll
    for (int i = 0; i < 16; i++) {
      int r = i * 4 + rb;
      int kk = kk0 + r;
      float val = (kk < OLDK) ? cv[(CACHE_BASE + kk) * (HH * DD) + h * DD + col]
                              : vin[(kk - OLDK) * (HH * DD) + h * DD + col];
      tl[r * 65 + col] = val;
    }
    __syncthreads();
#pragma unroll
    for (int i = 0; i < 16; i++) {
      int d = i * 4 + rb;
      Vt[(h * DD + d) * LW + kk0 + col] = f2bf(tl[col * 65 + d]);
    }
  } else if (b < 9216) {
    // K copy (old keys, already RoPE'd in cache): [kk][h][d] -> Kb[h][kk][d]
    int b1 = b - 2048;
    int h = b1 / 448, g = b1 % 448;
    int kk = g * 16 + (t >> 4);
    int lane = t & 15;
    float4 val = *(const float4*)(ck + (CACHE_BASE + kk) * (HH * DD) + h * DD + lane * 4);
    ushort4 o;
    o.x = f2bf(val.x); o.y = f2bf(val.y); o.z = f2bf(val.z); o.w = f2bf(val.w);
    *(ushort4*)(Kb + (h * LW + kk) * DD + lane * 4) = o;
  } else if (b < 11264) {
    // K rope (new keys)
    int b2 = b - 9216;
    int rh = b2 * 8 + (t >> 5);
    int s = rh >> 4, h = rh & 15, i = t & 31;
    float2 x = *(const float2*)(kin + s * (HH * DD) + h * DD + 2 * i);
    float c = fc[(SFRAME + s) * DD + 2 * i];
    float sn = fs[(SFRAME + s) * DD + 2 * i];
    ushort2 o;
    o.x = f2bf(x.x * c - x.y * sn);
    o.y = f2bf(x.y * c + x.x * sn);
    *(ushort2*)(Kb + (h * LW + OLDK + s) * DD + 2 * i) = o;
  } else {
    // Q rope + fold (1/sqrt(D)) * log2(e) so scores feed exp2 directly
    int b3 = b - 11264;
    int rh = b3 * 8 + (t >> 5);
    int s = rh >> 4, h = rh & 15, i = t & 31;
    const float SC = 0.18033688011112042f;  // 0.125 * log2(e)
    float2 x = *(const float2*)(qin + s * (HH * DD) + h * DD + 2 * i);
    float c = fc[(SFRAME + s) * DD + 2 * i];
    float sn = fs[(SFRAME + s) * DD + 2 * i];
    ushort2 o;
    o.x = f2bf((x.x * c - x.y * sn) * SC);
    o.y = f2bf((x.y * c + x.x * sn) * SC);
    *(ushort2*)(Qb + (h * SQ + s) * DD + 2 * i) = o;
  }
}

// ---------------- flash attention (no-max exp2 softmax, K-split) -------------
// grid: bid = g + 128*qb ; g = h + 16*ks. 4 waves x 64q = 256 q per block.
// P never touches LDS: C-layout -> B-operand via v_permlane32_swap_b32.
__global__ __launch_bounds__(256, 2) void attn(
    const unsigned short* __restrict__ Kb, const unsigned short* __restrict__ Vt,
    const unsigned short* __restrict__ Qb, float* __restrict__ Op,
    float* __restrict__ Lp) {
  __shared__ __align__(16) unsigned char sK[8192];           // 64kk x 64d bf16 (swizzled granules)
  __shared__ __align__(16) unsigned char sV[8192];           // 64d x 64kk bf16 (swizzled granules)

  int bid = blockIdx.x;
  int g = bid & 127, qb = bid >> 7;
  int h = g & 15, ks = g >> 4;
  int t = threadIdx.x;
  int w = t >> 6, lane = t & 63;
  int l31 = lane & 31, e = lane >> 5;
  int sw = l31 & 7;
  int q0 = qb * 256 + w * 64;

  // hoisted Q B-fragments, 2 q-tiles x 4 d-slices: B[k=d][n=q], n=l31, k=16c+8e+j
  bf16x8 qf[2][4];
#pragma unroll
  for (int tq = 0; tq < 2; tq++) {
    const unsigned short* qptr = Qb + (h * SQ + q0 + 32 * tq + l31) * DD + 8 * e;
#pragma unroll
    for (int c = 0; c < 4; c++) qf[tq][c] = *(const bf16x8*)(qptr + 16 * c);
  }

  floatx16 o[2][2];   // [tq][d-half], O^T[d][q]
#pragma unroll
  for (int a = 0; a < 2; a++)
#pragma unroll
    for (int bb = 0; bb < 2; bb++)
#pragma unroll
      for (int i = 0; i < 16; i++) o[a][bb][i] = 0.f;
  float ls[2] = {0.f, 0.f};

  const unsigned short* KbH = Kb + h * (LW * DD);
  const unsigned short* VtH = Vt + h * (DD * LW);
  int kkBase = ks * KPER;

  for (int st = 0; st < NSTEP; st++) {
    int kk0 = kkBase + st * 64;
    __syncthreads();
    // stage K-tile and V^T-tile, XOR-swizzled 16B granules
#pragma unroll
    for (int hf = 0; hf < 2; hf++) {
      int gi = w * 128 + hf * 64 + lane;
      int rr = gi >> 3;                       // kk for K, d for V
      int bs = (gi & 7) ^ (rr & 7);           // swizzled granule column
      async16(sK + gi * 16, KbH + (kk0 + rr) * DD + bs * 8);
      async16(sV + gi * 16, VtH + rr * LW + kk0 + bs * 8);
    }
    __syncthreads();

    // S^T[kk][q] = K . Q^T  (scores pre-scaled by 0.125*log2e via Qb)
    floatx16 s[2][2];   // [tq][kk-half]
#pragma unroll
    for (int a = 0; a < 2; a++)
#pragma unroll
      for (int bb = 0; bb < 2; bb++)
#pragma unroll
        for (int i = 0; i < 16; i++) s[a][bb][i] = 0.f;
#pragma unroll
    for (int c = 0; c < 4; c++) {
      int gsl = (2 * c + e) ^ sw;
      bf16x8 ka = *(const bf16x8*)(sK + (l31 * 8 + gsl) * 16);
      bf16x8 kb = *(const bf16x8*)(sK + ((l31 + 32) * 8 + gsl) * 16);
      s[0][0] = __builtin_amdgcn_mfma_f32_32x32x16_bf16(ka, qf[0][c], s[0][0], 0, 0, 0);
      s[0][1] = __builtin_amdgcn_mfma_f32_32x32x16_bf16(kb, qf[0][c], s[0][1], 0, 0, 0);
      s[1][0] = __builtin_amdgcn_mfma_f32_32x32x16_bf16(ka, qf[1][c], s[1][0], 0, 0, 0);
      s[1][1] = __builtin_amdgcn_mfma_f32_32x32x16_bf16(kb, qf[1][c], s[1][1], 0, 0, 0);
    }

    // P = exp2(S'); row-sums; pack to bf16x2 in C-layout register blocks
    unsigned pk[2][2][4][2];   // [tq][tk][block b][pair p]
#pragma unroll
    for (int tq = 0; tq < 2; tq++) {
#pragma unroll
      for (int tk = 0; tk < 2; tk++) {
#pragma unroll
        for (int i = 0; i < 16; i++) s[tq][tk][i] = fast_exp2(s[tq][tk][i]);
        float ps = 0.f;
#pragma unroll
        for (int i = 0; i < 16; i++) ps += s[tq][tk][i];
        ls[tq] += ps;
#pragma unroll
        for (int b = 0; b < 4; b++)
#pragma unroll
          for (int p = 0; p < 2; p++)
            pk[tq][tk][b][p] = pack_bf2(s[tq][tk][4 * b + 2 * p], s[tq][tk][4 * b + 2 * p + 1]);
      }
    }

    // C-layout -> B-operand layout: swap upper half of blk(2kc') with lower of blk(2kc'+1)
    bf16x8 pf[2][4];   // [tq][kc_global]
#pragma unroll
    for (int tq = 0; tq < 2; tq++) {
#pragma unroll
      for (int tk = 0; tk < 2; tk++) {
#pragma unroll
        for (int kcp = 0; kcp < 2; kcp++) {
          uintx2 r0 = __builtin_amdgcn_permlane32_swap(pk[tq][tk][2 * kcp][0],
                                                       pk[tq][tk][2 * kcp + 1][0], false, false);
          uintx2 r1 = __builtin_amdgcn_permlane32_swap(pk[tq][tk][2 * kcp][1],
                                                       pk[tq][tk][2 * kcp + 1][1], false, false);
          uintx4 f;
          f[0] = r0[0]; f[1] = r1[0]; f[2] = r0[1]; f[3] = r1[1];
          pf[tq][2 * tk + kcp] = __builtin_bit_cast(bf16x8, f);
        }
      }
    }

    // O^T[d][q] += V^T . P^T
#pragma unroll
    for (int kc = 0; kc < 4; kc++) {
      int gsl = (2 * kc + e) ^ sw;
      bf16x8 va = *(const bf16x8*)(sV + (l31 * 8 + gsl) * 16);
      bf16x8 vb = *(const bf16x8*)(sV + ((l31 + 32) * 8 + gsl) * 16);
      o[0][0] = __builtin_amdgcn_mfma_f32_32x32x16_bf16(va, pf[0][kc], o[0][0], 0, 0, 0);
      o[0][1] = __builtin_amdgcn_mfma_f32_32x32x16_bf16(vb, pf[0][kc], o[0][1], 0, 0, 0);
      o[1][0] = __builtin_amdgcn_mfma_f32_32x32x16_bf16(va, pf[1][kc], o[1][0], 0, 0, 0);
      o[1][1] = __builtin_amdgcn_mfma_f32_32x32x16_bf16(vb, pf[1][kc], o[1][1], 0, 0, 0);
    }
  }

  // epilogue: store split numerators + denominators
#pragma unroll
  for (int tq = 0; tq < 2; tq++) {
    float l = ls[tq];
    l += __shfl_xor(l, 32, 64);
    int qrow = q0 + 32 * tq + l31;
    float* op = Op + (((ks * 16 + h) * SQ) + qrow) * DD;
#pragma unroll
    for (int t4 = 0; t4 < 4; t4++) {
      float4 a, b;
      a.x = o[tq][0][4 * t4 + 0]; a.y = o[tq][0][4 * t4 + 1];
      a.z = o[tq][0][4 * t4 + 2]; a.w = o[tq][0][4 * t4 + 3];
      b.x = o[tq][1][4 * t4 + 0]; b.y = o[tq][1][4 * t4 + 1];
      b.z = o[tq][1][4 * t4 + 2]; b.w = o[tq][1][4 * t4 + 3];
      *(float4*)(op + 8 * t4 + 4 * e) = a;         // d = 8t4+4e+0..3
      *(float4*)(op + 32 + 8 * t4 + 4 * e) = b;    // d = 32+8t4+4e+0..3
    }
    if (e == 0) Lp[(ks * 16 + h) * SQ + qrow] = l;
  }
}

// ---------------- combine splits ----------------
__global__ __launch_bounds__(256) void combine(const float* __restrict__ Op,
                                               const float* __restrict__ Lp,
                                               float* __restrict__ out) {
  int idx = blockIdx.x * 256 + threadIdx.x;
  int d = idx & 63, q = (idx >> 6) & 1023, h = idx >> 16;
  float num = 0.f, den = 0.f;
#pragma unroll
  for (int s = 0; s < KSPLIT; s++) {
    int row = (s * 16 + h) * SQ + q;
    num += Op[row * DD + d];
    den += Lp[row];
  }
  out[q * (HH * DD) + h * DD + d] = num / den;
}

extern "C" void kernel_launch(void* const* d_in, const int* in_sizes, int n_in,
                              void* d_out, int out_size, void* d_ws, size_t ws_size,
                              hipStream_t stream) {
  const float* q  = (const float*)d_in[0];
  const float* k  = (const float*)d_in[1];
  const float* v  = (const float*)d_in[2];
  const float* ck = (const float*)d_in[3];
  const float* cv = (const float*)d_in[4];
  const float* fc = (const float*)d_in[5];
  const float* fs = (const float*)d_in[6];
  float* out = (float*)d_out;
  char* ws = (char*)d_ws;

  unsigned short* Kb = (unsigned short*)(ws + KB_OFF);
  unsigned short* Vt = (unsigned short*)(ws + VT_OFF);
  unsigned short* Qb = (unsigned short*)(ws + QB_OFF);
  float* Op = (float*)(ws + OP_OFF);
  float* Lp = (float*)(ws + LP_OFF);

  prepass<<<13312, 256, 0, stream>>>(q, k, v, ck, cv, fc, fs, Kb, Vt, Qb);
  attn<<<512, 256, 0, stream>>>(Kb, Vt, Qb, Op, Lp);
  combine<<<4096, 256, 0, stream>>>(Op, Lp, out);
}